// Round 1
// baseline (34331.039 us; speedup 1.0000x reference)
//
#include <hip/hip_runtime.h>
#include <math.h>

#define Bdim 32
#define Sdim 128
#define Tdim 50
#define Edim 768
#define Hdim 1024
#define Vdim 32000
#define EH   1792   // E + H, row stride of attn_W1
#define INPD 1536   // 2*E, LSTM layer-0 input dim

__device__ __forceinline__ float sigmf(float v){ return 1.0f / (1.0f + expf(-v)); }

// ---------------- init: zero h/c state buffers ----------------
__global__ __launch_bounds__(256) void zero_kernel(float* __restrict__ p, int n){
  int i = blockIdx.x * 256 + threadIdx.x;
  if (i < n) p[i] = 0.0f;
}

// ---------------- gather embedding rows into per-step input buffers ----------------
// inp_all layout: (T, B, 1536): [0,768) = emb(target), [768,1536) = context (filled per step)
__global__ __launch_bounds__(256) void gather_emb(const int* __restrict__ tseq,
                                                  const float* __restrict__ emb,
                                                  float* __restrict__ inp_all){
  int idx = blockIdx.x * 256 + threadIdx.x;
  if (idx >= Tdim * Bdim * Edim) return;
  int e = idx % Edim;
  int r = idx / Edim;
  int b = r % Bdim;
  int t = r / Bdim;
  int tok = tseq[b * Tdim + t];
  inp_all[(size_t)(t * Bdim + b) * INPD + e] = emb[(size_t)tok * Edim + e];
}

// ---------------- xW = x @ W1x^T  (M=4096, N=1024, K=768), tiled 64x64x16 ----------------
__global__ __launch_bounds__(256) void xw_gemm(const float* __restrict__ x,
                                               const float* __restrict__ w1,
                                               float* __restrict__ xW){
  __shared__ float As[16][68];
  __shared__ float Ws[16][68];
  int tid = threadIdx.x;
  int m0 = blockIdx.x * 64;
  int n0 = blockIdx.y * 64;
  int lm = tid >> 2;         // 0..63 row being loaded
  int lk = (tid & 3) << 2;   // 0,4,8,12
  int tm = (tid >> 4) << 2;  // thread tile row
  int tn = (tid & 15) << 2;  // thread tile col
  float acc[4][4] = {};
  for (int k0 = 0; k0 < Edim; k0 += 16){
    float4 av = *(const float4*)&x [(size_t)(m0 + lm) * Edim + k0 + lk];
    float4 wv = *(const float4*)&w1[(size_t)(n0 + lm) * EH   + k0 + lk];
    As[lk+0][lm] = av.x; As[lk+1][lm] = av.y; As[lk+2][lm] = av.z; As[lk+3][lm] = av.w;
    Ws[lk+0][lm] = wv.x; Ws[lk+1][lm] = wv.y; Ws[lk+2][lm] = wv.z; Ws[lk+3][lm] = wv.w;
    __syncthreads();
#pragma unroll
    for (int k = 0; k < 16; k++){
      float a0 = As[k][tm+0], a1 = As[k][tm+1], a2 = As[k][tm+2], a3 = As[k][tm+3];
      float b0 = Ws[k][tn+0], b1 = Ws[k][tn+1], b2 = Ws[k][tn+2], b3 = Ws[k][tn+3];
      acc[0][0] += a0*b0; acc[0][1] += a0*b1; acc[0][2] += a0*b2; acc[0][3] += a0*b3;
      acc[1][0] += a1*b0; acc[1][1] += a1*b1; acc[1][2] += a1*b2; acc[1][3] += a1*b3;
      acc[2][0] += a2*b0; acc[2][1] += a2*b1; acc[2][2] += a2*b2; acc[2][3] += a2*b3;
      acc[3][0] += a3*b0; acc[3][1] += a3*b1; acc[3][2] += a3*b2; acc[3][3] += a3*b3;
    }
    __syncthreads();
  }
#pragma unroll
  for (int i = 0; i < 4; i++)
#pragma unroll
    for (int j = 0; j < 4; j++)
      xW[(size_t)(m0 + tm + i) * Hdim + n0 + tn + j] = acc[i][j];
}

// ---------------- a = h2 @ W1h^T  (B=32 x H=1024, K=1024) ----------------
// block: 256 threads = 32 b x 8 j; weight rows broadcast across the 32 b-lanes
__global__ __launch_bounds__(256) void attn_a(const float* __restrict__ h2,
                                              const float* __restrict__ w1,
                                              float* __restrict__ aBuf){
  int tid = threadIdx.x;
  int b = tid & 31, jj = tid >> 5;
  int j = blockIdx.x * 8 + jj;
  const float* hrow = h2 + (size_t)b * Hdim;
  const float* wrow = w1 + (size_t)j * EH + Edim;   // W1h row
  float acc = 0.0f;
  for (int k = 0; k < Hdim; k += 4){
    float4 hv = *(const float4*)&hrow[k];
    float4 wv = *(const float4*)&wrow[k];
    acc += hv.x*wv.x + hv.y*wv.y + hv.z*wv.z + hv.w*wv.w;
  }
  aBuf[b * Hdim + j] = acc;
}

// ---------------- scores -> log_softmax over S -> context; one block per batch ----------------
__global__ __launch_bounds__(256) void attn_ctx(const float* __restrict__ xW,
                                                const float* __restrict__ aBuf,
                                                const float* __restrict__ b1,
                                                const float* __restrict__ w2,
                                                const float* __restrict__ b2p,
                                                const float* __restrict__ x,
                                                float* __restrict__ inp_t){
  __shared__ float sc[Sdim];
  int b = blockIdx.x, tid = threadIdx.x;
  int wv = tid >> 6, lane = tid & 63;
  const float* arow = aBuf + b * Hdim;
  // phase 1: scores[s] = sum_j relu(xW + a + b1) * w2
  for (int s = wv; s < Sdim; s += 4){
    const float* xwrow = xW + (size_t)(b * Sdim + s) * Hdim;
    float acc = 0.0f;
    for (int j = lane; j < Hdim; j += 64){
      float hv = xwrow[j] + arow[j] + b1[j];
      hv = fmaxf(hv, 0.0f);
      acc += hv * w2[j];
    }
    for (int off = 32; off > 0; off >>= 1) acc += __shfl_down(acc, off);
    if (lane == 0) sc[s] = acc + b2p[0];
  }
  __syncthreads();
  // phase 2: log_softmax over the 128 scores (wave 0)
  if (wv == 0){
    float v0 = sc[lane], v1 = sc[lane + 64];
    float m = fmaxf(v0, v1);
    for (int off = 32; off > 0; off >>= 1) m = fmaxf(m, __shfl_xor(m, off));
    float e = expf(v0 - m) + expf(v1 - m);
    for (int off = 32; off > 0; off >>= 1) e += __shfl_xor(e, off);
    float lse = m + logf(e);
    sc[lane]      = v0 - lse;
    sc[lane + 64] = v1 - lse;
  }
  __syncthreads();
  // phase 3: context[e] = sum_s logw[s] * x[b,s,e]
  for (int e = tid; e < Edim; e += 256){
    float acc = 0.0f;
    for (int s = 0; s < Sdim; s++) acc += sc[s] * x[(size_t)(b * Sdim + s) * Edim + e];
    inp_t[b * INPD + Edim + e] = acc;
  }
}

// ---------------- LSTM layer: gates GEMM + fused cell update ----------------
// grid 512 blocks x 2 units; 256 threads = 32 b x 2 u x 4 K-split groups.
// Each thread computes partial i,f,g,o dots for unit j; kh=0 finishes + cell update.
__global__ __launch_bounds__(256) void lstm_gate(const float* __restrict__ inp, int in_dim,
                                                 const float* __restrict__ hold,
                                                 const float* __restrict__ Wih,
                                                 const float* __restrict__ Whh,
                                                 const float* __restrict__ bih,
                                                 const float* __restrict__ bhh,
                                                 const float* __restrict__ cold,
                                                 float* __restrict__ hnew,
                                                 float* __restrict__ cnew){
  __shared__ float part[3][4][2][32];
  int tid = threadIdx.x;
  int b  = tid & 31;
  int u  = (tid >> 5) & 1;
  int kh = tid >> 6;          // 0..3
  int j  = blockIdx.x * 2 + u;
  const float* src; const float* wb; int ld, kbeg, klen;
  if (kh < 2){ src = inp  + (size_t)b * in_dim; wb = Wih; ld = in_dim; klen = in_dim >> 1; kbeg = kh * klen; }
  else       { src = hold + (size_t)b * Hdim;   wb = Whh; ld = Hdim;   klen = Hdim >> 1;   kbeg = (kh - 2) * klen; }
  const float* w0 = wb + (size_t)(j           ) * ld + kbeg;
  const float* w1 = wb + (size_t)(j +     Hdim) * ld + kbeg;
  const float* w2 = wb + (size_t)(j + 2 * Hdim) * ld + kbeg;
  const float* w3 = wb + (size_t)(j + 3 * Hdim) * ld + kbeg;
  src += kbeg;
  float a0 = 0, a1 = 0, a2 = 0, a3 = 0;
  for (int k = 0; k < klen; k += 4){
    float4 v  = *(const float4*)&src[k];
    float4 q0 = *(const float4*)&w0[k]; a0 += v.x*q0.x + v.y*q0.y + v.z*q0.z + v.w*q0.w;
    float4 q1 = *(const float4*)&w1[k]; a1 += v.x*q1.x + v.y*q1.y + v.z*q1.z + v.w*q1.w;
    float4 q2 = *(const float4*)&w2[k]; a2 += v.x*q2.x + v.y*q2.y + v.z*q2.z + v.w*q2.w;
    float4 q3 = *(const float4*)&w3[k]; a3 += v.x*q3.x + v.y*q3.y + v.z*q3.z + v.w*q3.w;
  }
  if (kh > 0){
    part[kh-1][0][u][b] = a0;
    part[kh-1][1][u][b] = a1;
    part[kh-1][2][u][b] = a2;
    part[kh-1][3][u][b] = a3;
  }
  __syncthreads();
  if (kh == 0){
    float gi = a0 + part[0][0][u][b] + part[1][0][u][b] + part[2][0][u][b] + bih[j]          + bhh[j];
    float gf = a1 + part[0][1][u][b] + part[1][1][u][b] + part[2][1][u][b] + bih[j +   Hdim] + bhh[j +   Hdim];
    float gg = a2 + part[0][2][u][b] + part[1][2][u][b] + part[2][2][u][b] + bih[j + 2*Hdim] + bhh[j + 2*Hdim];
    float go = a3 + part[0][3][u][b] + part[1][3][u][b] + part[2][3][u][b] + bih[j + 3*Hdim] + bhh[j + 3*Hdim];
    float cv = sigmf(gf) * cold[b * Hdim + j] + sigmf(gi) * tanhf(gg);
    float hv = sigmf(go) * tanhf(cv);
    cnew[b * Hdim + j] = cv;
    hnew[b * Hdim + j] = hv;
  }
}

// ---------------- logits = h2 @ fc_W^T + fc_b  (M=32, N=32000, K=1024) ----------------
// block: 32 v-rows x 32 b; thread handles 4 v-rows (register reuse of the LDS h-value).
__global__ __launch_bounds__(256) void fc_kernel(const float* __restrict__ h2,
                                                 const float* __restrict__ fcW,
                                                 const float* __restrict__ fcb,
                                                 float* __restrict__ logits){
  __shared__ float sh[32 * 260];   // [b][k], stride 260 (16B-aligned rows, 4-way bank alias ok)
  int tid = threadIdx.x;
  int b  = tid & 31;
  int vv = tid >> 5;
  int v0 = blockIdx.x * 32 + vv * 4;
  float acc0 = 0, acc1 = 0, acc2 = 0, acc3 = 0;
  for (int k0 = 0; k0 < Hdim; k0 += 256){
    __syncthreads();
    for (int i = tid; i < 2048; i += 256){      // 32 rows x 64 float4
      int bb = i >> 6;
      int kk = (i & 63) << 2;
      *(float4*)&sh[bb * 260 + kk] = *(const float4*)&h2[(size_t)bb * Hdim + k0 + kk];
    }
    __syncthreads();
    const float* w0 = fcW + (size_t)(v0 + 0) * Hdim + k0;
    const float* w1 = fcW + (size_t)(v0 + 1) * Hdim + k0;
    const float* w2 = fcW + (size_t)(v0 + 2) * Hdim + k0;
    const float* w3 = fcW + (size_t)(v0 + 3) * Hdim + k0;
    const float* hv = &sh[b * 260];
    for (int k = 0; k < 256; k += 4){
      float4 h4 = *(const float4*)&hv[k];
      float4 q0 = *(const float4*)&w0[k]; acc0 += h4.x*q0.x + h4.y*q0.y + h4.z*q0.z + h4.w*q0.w;
      float4 q1 = *(const float4*)&w1[k]; acc1 += h4.x*q1.x + h4.y*q1.y + h4.z*q1.z + h4.w*q1.w;
      float4 q2 = *(const float4*)&w2[k]; acc2 += h4.x*q2.x + h4.y*q2.y + h4.z*q2.z + h4.w*q2.w;
      float4 q3 = *(const float4*)&w3[k]; acc3 += h4.x*q3.x + h4.y*q3.y + h4.z*q3.z + h4.w*q3.w;
    }
  }
  logits[(size_t)b * Vdim + v0 + 0] = acc0 + fcb[v0 + 0];
  logits[(size_t)b * Vdim + v0 + 1] = acc1 + fcb[v0 + 1];
  logits[(size_t)b * Vdim + v0 + 2] = acc2 + fcb[v0 + 2];
  logits[(size_t)b * Vdim + v0 + 3] = acc3 + fcb[v0 + 3];
}

// ---------------- log_softmax over V and write output ----------------
__global__ __launch_bounds__(256) void lsm_kernel(const float* __restrict__ logits,
                                                  float* __restrict__ out, int t){
  __shared__ float red[256];
  int b = blockIdx.x, tid = threadIdx.x;
  const float4* row4 = (const float4*)(logits + (size_t)b * Vdim);
  float m = -1e30f;
  for (int i = tid; i < Vdim / 4; i += 256){
    float4 v = row4[i];
    m = fmaxf(m, fmaxf(fmaxf(v.x, v.y), fmaxf(v.z, v.w)));
  }
  red[tid] = m; __syncthreads();
  for (int s2 = 128; s2 > 0; s2 >>= 1){
    if (tid < s2) red[tid] = fmaxf(red[tid], red[tid + s2]);
    __syncthreads();
  }
  m = red[0]; __syncthreads();
  float sum = 0.0f;
  for (int i = tid; i < Vdim / 4; i += 256){
    float4 v = row4[i];
    sum += expf(v.x - m) + expf(v.y - m) + expf(v.z - m) + expf(v.w - m);
  }
  red[tid] = sum; __syncthreads();
  for (int s2 = 128; s2 > 0; s2 >>= 1){
    if (tid < s2) red[tid] += red[tid + s2];
    __syncthreads();
  }
  float lse = m + logf(red[0]);
  float4* o4 = (float4*)(out + (size_t)(b * Tdim + t) * Vdim);
  for (int i = tid; i < Vdim / 4; i += 256){
    float4 v = row4[i];
    o4[i] = make_float4(v.x - lse, v.y - lse, v.z - lse, v.w - lse);
  }
}

extern "C" void kernel_launch(void* const* d_in, const int* in_sizes, int n_in,
                              void* d_out, int out_size, void* d_ws, size_t ws_size,
                              hipStream_t stream){
  const float* x    = (const float*)d_in[0];
  const int*   tseq = (const int*)  d_in[1];
  const float* emb  = (const float*)d_in[2];
  const float* aW1  = (const float*)d_in[3];
  const float* ab1  = (const float*)d_in[4];
  const float* aW2  = (const float*)d_in[5];
  const float* ab2  = (const float*)d_in[6];
  const float* fcW  = (const float*)d_in[7];
  const float* fcb  = (const float*)d_in[8];
  const float* Wih[3] = {(const float*)d_in[9],  (const float*)d_in[13], (const float*)d_in[17]};
  const float* Whh[3] = {(const float*)d_in[10], (const float*)d_in[14], (const float*)d_in[18]};
  const float* bih[3] = {(const float*)d_in[11], (const float*)d_in[15], (const float*)d_in[19]};
  const float* bhh[3] = {(const float*)d_in[12], (const float*)d_in[16], (const float*)d_in[20]};
  float* out = (float*)d_out;

  // workspace layout (floats): ~8.0M floats = 32.1 MB
  float* ws      = (float*)d_ws;
  float* xW      = ws;                                   // 4096*1024
  float* inp_all = xW + (size_t)4096 * 1024;             // 50*32*1536
  float* aBuf    = inp_all + (size_t)Tdim * Bdim * INPD; // 32*1024
  float* hA      = aBuf + Bdim * Hdim;                   // 3*32*1024
  float* hB      = hA + 3 * Bdim * Hdim;
  float* cA      = hB + 3 * Bdim * Hdim;
  float* cB      = cA + 3 * Bdim * Hdim;
  float* logits  = cB + 3 * Bdim * Hdim;                 // 32*32000

  zero_kernel<<<(4 * 3 * Bdim * Hdim + 255) / 256, 256, 0, stream>>>(hA, 4 * 3 * Bdim * Hdim);
  gather_emb<<<(Tdim * Bdim * Edim + 255) / 256, 256, 0, stream>>>(tseq, emb, inp_all);
  xw_gemm<<<dim3(64, 16), 256, 0, stream>>>(x, aW1, xW);

  for (int t = 0; t < Tdim; t++){
    float* h_old = (t & 1) ? hB : hA;
    float* h_cur = (t & 1) ? hA : hB;
    float* c_old = (t & 1) ? cB : cA;
    float* c_cur = (t & 1) ? cA : cB;
    float* inp_t = inp_all + (size_t)t * Bdim * INPD;

    attn_a<<<128, 256, 0, stream>>>(h_old + 2 * Bdim * Hdim, aW1, aBuf);
    attn_ctx<<<32, 256, 0, stream>>>(xW, aBuf, ab1, aW2, ab2, x, inp_t);
    lstm_gate<<<512, 256, 0, stream>>>(inp_t, INPD, h_old, Wih[0], Whh[0], bih[0], bhh[0],
                                       c_old, h_cur, c_cur);
    lstm_gate<<<512, 256, 0, stream>>>(h_cur, Hdim, h_old + Bdim * Hdim, Wih[1], Whh[1], bih[1], bhh[1],
                                       c_old + Bdim * Hdim, h_cur + Bdim * Hdim, c_cur + Bdim * Hdim);
    lstm_gate<<<512, 256, 0, stream>>>(h_cur + Bdim * Hdim, Hdim, h_old + 2 * Bdim * Hdim, Wih[2], Whh[2], bih[2], bhh[2],
                                       c_old + 2 * Bdim * Hdim, h_cur + 2 * Bdim * Hdim, c_cur + 2 * Bdim * Hdim);
    fc_kernel<<<Vdim / 32, 256, 0, stream>>>(h_cur + 2 * Bdim * Hdim, fcW, fcb, logits);
    lsm_kernel<<<Bdim, 256, 0, stream>>>(logits, out, t);
  }
}

// Round 2
// 4855.173 us; speedup vs baseline: 7.0710x; 7.0710x over previous
//
#include <hip/hip_runtime.h>
#include <math.h>

#define Bdim 32
#define Sdim 128
#define Tdim 50
#define Edim 768
#define Hdim 1024
#define Vdim 32000
#define EH   1792
#define INPD 1536

typedef __bf16 bf16x8 __attribute__((ext_vector_type(8)));
typedef float  f32x4  __attribute__((ext_vector_type(4)));

__device__ __forceinline__ float sigmf(float v){ return 1.0f / (1.0f + expf(-v)); }

__device__ __forceinline__ ushort f2b(float v){
  unsigned int b = __float_as_uint(v);
  unsigned int r = (b + 0x7fffu + ((b >> 16) & 1u)) >> 16;
  return (ushort)r;
}
__device__ __forceinline__ float b2f(ushort u){
  return __uint_as_float(((unsigned int)u) << 16);
}

// ============ generic f32 -> bf16 convert (n multiple of 4) ============
__global__ __launch_bounds__(256) void cvt_bf16(const float* __restrict__ src,
                                                ushort* __restrict__ dst, int n4){
  int i = blockIdx.x * 256 + threadIdx.x;
  if (i >= n4) return;
  float4 v = *(const float4*)(src + (size_t)i * 4);
  *(ushort4*)(dst + (size_t)i * 4) = make_ushort4(f2b(v.x), f2b(v.y), f2b(v.z), f2b(v.w));
}

// W1h_bf[j][k] = attn_W1[j][768+k], j,k in [0,1024)
__global__ __launch_bounds__(256) void cvt_w1h(const float* __restrict__ aW1,
                                               ushort* __restrict__ dst){
  int i = blockIdx.x * 256 + threadIdx.x;   // float4 groups, 262144 total
  if (i >= 262144) return;
  int k = (i & 255) * 4;
  int j = i >> 8;
  float4 v = *(const float4*)(aW1 + (size_t)j * EH + Edim + k);
  *(ushort4*)(dst + (size_t)j * 1024 + k) = make_ushort4(f2b(v.x), f2b(v.y), f2b(v.z), f2b(v.w));
}

__global__ __launch_bounds__(256) void zero_kernel(float* __restrict__ p, int n){
  int i = blockIdx.x * 256 + threadIdx.x;
  if (i < n) p[i] = 0.0f;
}

// ============ gather embeddings -> packed bf16 inp buffers (emb part) ============
// packed layout per t: [k/8][b(32)][8] ushorts, k in [0,1536); emb fills k<768
__global__ __launch_bounds__(256) void gather_emb_p(const int* __restrict__ tseq,
                                                    const float* __restrict__ emb,
                                                    ushort* __restrict__ inpP){
  int g = blockIdx.x * 256 + threadIdx.x;   // groups of 8: T*B*96
  if (g >= Tdim * Bdim * 96) return;
  int kb = g % 96;
  int r = g / 96;
  int b = r % Bdim;
  int t = r / Bdim;
  int tok = tseq[b * Tdim + t];
  const float* src = emb + (size_t)tok * Edim + kb * 8;
  float4 a = *(const float4*)src;
  float4 c = *(const float4*)(src + 4);
  ushort* dst = inpP + (size_t)t * 49152 + kb * 256 + b * 8;
  *(ushort4*)(dst)     = make_ushort4(f2b(a.x), f2b(a.y), f2b(a.z), f2b(a.w));
  *(ushort4*)(dst + 4) = make_ushort4(f2b(c.x), f2b(c.y), f2b(c.z), f2b(c.w));
}

// ============ xW = x @ W1x^T -> bf16 (M=4096, N=1024, K=768) ============
__global__ __launch_bounds__(256) void xw_gemm(const float* __restrict__ x,
                                               const float* __restrict__ w1,
                                               ushort* __restrict__ xWb){
  __shared__ float As[16][68];
  __shared__ float Ws[16][68];
  int tid = threadIdx.x;
  int m0 = blockIdx.x * 64;
  int n0 = blockIdx.y * 64;
  int lm = tid >> 2;
  int lk = (tid & 3) << 2;
  int tm = (tid >> 4) << 2;
  int tn = (tid & 15) << 2;
  float acc[4][4] = {};
  for (int k0 = 0; k0 < Edim; k0 += 16){
    float4 av = *(const float4*)&x [(size_t)(m0 + lm) * Edim + k0 + lk];
    float4 wv = *(const float4*)&w1[(size_t)(n0 + lm) * EH   + k0 + lk];
    As[lk+0][lm] = av.x; As[lk+1][lm] = av.y; As[lk+2][lm] = av.z; As[lk+3][lm] = av.w;
    Ws[lk+0][lm] = wv.x; Ws[lk+1][lm] = wv.y; Ws[lk+2][lm] = wv.z; Ws[lk+3][lm] = wv.w;
    __syncthreads();
#pragma unroll
    for (int k = 0; k < 16; k++){
      float a0 = As[k][tm+0], a1 = As[k][tm+1], a2 = As[k][tm+2], a3 = As[k][tm+3];
      float b0 = Ws[k][tn+0], b1 = Ws[k][tn+1], b2 = Ws[k][tn+2], b3 = Ws[k][tn+3];
      acc[0][0] += a0*b0; acc[0][1] += a0*b1; acc[0][2] += a0*b2; acc[0][3] += a0*b3;
      acc[1][0] += a1*b0; acc[1][1] += a1*b1; acc[1][2] += a1*b2; acc[1][3] += a1*b3;
      acc[2][0] += a2*b0; acc[2][1] += a2*b1; acc[2][2] += a2*b2; acc[2][3] += a2*b3;
      acc[3][0] += a3*b0; acc[3][1] += a3*b1; acc[3][2] += a3*b2; acc[3][3] += a3*b3;
    }
    __syncthreads();
  }
#pragma unroll
  for (int i = 0; i < 4; i++)
#pragma unroll
    for (int j = 0; j < 4; j++)
      xWb[(size_t)(m0 + tm + i) * Hdim + n0 + tn + j] = f2b(acc[i][j]);
}

// ============ MFMA tile helper: 16 rows x 32 b, K-range accumulate ============
// A row-major (lda elems). B packed [k/8][32][8] bf16.
// acc0 = b-cols 0..15, acc1 = 16..31. D mapping: row=(lane>>4)*4+reg, col=lane&15.
template<bool ABF16>
__device__ __forceinline__ void mfma_tile(const void* A, int lda, int rowBase,
                                          const ushort* __restrict__ Bp,
                                          int kbeg, int klen, int lane,
                                          f32x4& acc0, f32x4& acc1){
  int r = rowBase + (lane & 15);
  int q = lane >> 4;
  const ushort* Ab = (const ushort*)A;
  const float*  Af = (const float*)A;
#pragma unroll 4
  for (int kk = kbeg; kk < kbeg + klen; kk += 32){
    bf16x8 a;
    if (ABF16){
      a = *reinterpret_cast<const bf16x8*>(Ab + (size_t)r * lda + kk + q * 8);
    } else {
      const float* p = Af + (size_t)r * lda + kk + q * 8;
      float4 u = *(const float4*)p;
      float4 w = *(const float4*)(p + 4);
      union { ushort s[8]; bf16x8 v; } t;
      t.s[0]=f2b(u.x); t.s[1]=f2b(u.y); t.s[2]=f2b(u.z); t.s[3]=f2b(u.w);
      t.s[4]=f2b(w.x); t.s[5]=f2b(w.y); t.s[6]=f2b(w.z); t.s[7]=f2b(w.w);
      a = t.v;
    }
    const ushort* bbase = Bp + ((kk >> 3) + q) * 256 + (lane & 15) * 8;
    bf16x8 b0 = *reinterpret_cast<const bf16x8*>(bbase);
    bf16x8 b1 = *reinterpret_cast<const bf16x8*>(bbase + 128);
    acc0 = __builtin_amdgcn_mfma_f32_16x16x32_bf16(a, b0, acc0, 0, 0, 0);
    acc1 = __builtin_amdgcn_mfma_f32_16x16x32_bf16(a, b1, acc1, 0, 0, 0);
  }
}

// ============ LSTM gate GEMM: rows=4096 gate-rows, b=32, K split 4 ways ============
// grid (64, 4); partial[kq][row][b]
template<bool ABF16>
__global__ __launch_bounds__(256) void gate_gemm(const void* __restrict__ Wih, int Kin,
                                                 const void* __restrict__ Whh,
                                                 const ushort* __restrict__ inpP,
                                                 const ushort* __restrict__ hP,
                                                 float* __restrict__ part){
  int lane = threadIdx.x & 63, w = threadIdx.x >> 6;
  int rowBase = blockIdx.x * 64 + w * 16;
  int kq = blockIdx.y;
  f32x4 acc0 = {0,0,0,0}, acc1 = {0,0,0,0};
  if (kq < 2) mfma_tile<ABF16>(Wih, Kin, rowBase, inpP, kq * (Kin >> 1), Kin >> 1, lane, acc0, acc1);
  else        mfma_tile<ABF16>(Whh, Hdim, rowBase, hP, (kq - 2) * 512, 512, lane, acc0, acc1);
  float* dst = part + (size_t)kq * (4096 * 32);
  int q = lane >> 4, c = lane & 15;
#pragma unroll
  for (int rr = 0; rr < 4; rr++){
    int row = rowBase + q * 4 + rr;
    dst[row * 32 + c]      = acc0[rr];
    dst[row * 32 + 16 + c] = acc1[rr];
  }
}

// ============ cell update + pack h to bf16 [k/8][b][8] ============
__global__ __launch_bounds__(256) void cell_update(const float* __restrict__ part,
                                                   const float* __restrict__ bih,
                                                   const float* __restrict__ bhh,
                                                   const float* __restrict__ cold,
                                                   float* __restrict__ cnew,
                                                   ushort* __restrict__ hPack){
  int idx = blockIdx.x * 256 + threadIdx.x;   // 32768
  int b = idx & 31, j = idx >> 5;
  float gi = 0, gf = 0, gg = 0, go = 0;
#pragma unroll
  for (int kq = 0; kq < 4; kq++){
    const float* p = part + (size_t)kq * 131072;
    gi += p[j * 32 + b];
    gf += p[(j + 1024) * 32 + b];
    gg += p[(j + 2048) * 32 + b];
    go += p[(j + 3072) * 32 + b];
  }
  gi += bih[j]        + bhh[j];
  gf += bih[j + 1024] + bhh[j + 1024];
  gg += bih[j + 2048] + bhh[j + 2048];
  go += bih[j + 3072] + bhh[j + 3072];
  float cv = sigmf(gf) * cold[j * 32 + b] + sigmf(gi) * tanhf(gg);
  float hv = sigmf(go) * tanhf(cv);
  cnew[j * 32 + b] = cv;
  hPack[(j >> 3) * 256 + b * 8 + (j & 7)] = f2b(hv);
}

// ============ attn pre-activation: a = h2_old @ W1h^T, partials [kq][b][j] ============
__global__ __launch_bounds__(256) void attn_a_gemm(const ushort* __restrict__ W1h,
                                                   const ushort* __restrict__ h2P,
                                                   float* __restrict__ part){
  int lane = threadIdx.x & 63, w = threadIdx.x >> 6;
  int rowBase = blockIdx.x * 64 + w * 16;
  int kq = blockIdx.y;
  f32x4 acc0 = {0,0,0,0}, acc1 = {0,0,0,0};
  mfma_tile<true>(W1h, Hdim, rowBase, h2P, kq * 256, 256, lane, acc0, acc1);
  float* dst = part + (size_t)kq * 32768;
  int q = lane >> 4, c = lane & 15;
#pragma unroll
  for (int rr = 0; rr < 4; rr++){
    int row = rowBase + q * 4 + rr;              // j
    dst[c * 1024 + row]        = acc0[rr];
    dst[(c + 16) * 1024 + row] = acc1[rr];
  }
}

// ============ scores[b][s] = relu(xW+a+b1) . w2 + b2 ============
// grid 128 = b(32) x sg(4); wave handles 8 s-values, lanes span j
__global__ __launch_bounds__(256) void attn_score(const float* __restrict__ aPart,
                                                  const float* __restrict__ b1,
                                                  const float* __restrict__ w2,
                                                  const float* __restrict__ b2p,
                                                  const ushort* __restrict__ xWb,
                                                  float* __restrict__ scBuf){
  int b = blockIdx.x >> 2, sg = blockIdx.x & 3;
  int w = threadIdx.x >> 6, lane = threadIdx.x & 63;
  float ab[16], wv[16];
#pragma unroll
  for (int i = 0; i < 16; i++){
    int j = lane + 64 * i;
    float av = aPart[b * 1024 + j] + aPart[32768 + b * 1024 + j]
             + aPart[65536 + b * 1024 + j] + aPart[98304 + b * 1024 + j];
    ab[i] = av + b1[j];
    wv[i] = w2[j];
  }
  float b2v = b2p[0];
#pragma unroll
  for (int si = 0; si < 8; si++){
    int s = sg * 32 + w * 8 + si;
    const ushort* xrow = xWb + (size_t)(b * Sdim + s) * Hdim;
    float acc = 0.0f;
#pragma unroll
    for (int i = 0; i < 16; i++){
      float xv = b2f(xrow[lane + 64 * i]);
      float hv = fmaxf(xv + ab[i], 0.0f);
      acc += hv * wv[i];
    }
    for (int off = 32; off; off >>= 1) acc += __shfl_xor(acc, off);
    if (lane == 0) scBuf[b * Sdim + s] = acc + b2v;
  }
}

// ============ log-softmax(scores) + context -> packed bf16 inp (k=768..1535) ============
// grid 96 = b(32) x ec(3); thread owns e = ec*256+tid
__global__ __launch_bounds__(256) void attn_ctx2(const float* __restrict__ scBuf,
                                                 const float* __restrict__ x,
                                                 ushort* __restrict__ inpPt){
  __shared__ float sb[Sdim];
  __shared__ float lseS;
  int b = blockIdx.x / 3, ec = blockIdx.x % 3;
  int tid = threadIdx.x;
  if (tid < Sdim) sb[tid] = scBuf[b * Sdim + tid];
  __syncthreads();
  if (tid < 64){
    float v0 = sb[tid], v1 = sb[tid + 64];
    float m = fmaxf(v0, v1);
    for (int off = 32; off; off >>= 1) m = fmaxf(m, __shfl_xor(m, off));
    float e = expf(v0 - m) + expf(v1 - m);
    for (int off = 32; off; off >>= 1) e += __shfl_xor(e, off);
    if (tid == 0) lseS = m + logf(e);
  }
  __syncthreads();
  float lse = lseS;
  int e = ec * 256 + tid;
  const float* xb = x + (size_t)b * Sdim * Edim + e;
  float acc = 0.0f;
#pragma unroll 8
  for (int s = 0; s < Sdim; s++) acc += (sb[s] - lse) * xb[(size_t)s * Edim];
  int k = Edim + e;
  inpPt[(k >> 3) * 256 + b * 8 + (k & 7)] = f2b(acc);
}

// ============ fc: logits[b][v], grid 500 blocks of 64 v-rows ============
template<bool ABF16>
__global__ __launch_bounds__(256) void fc_gemm(const void* __restrict__ fcW,
                                               const ushort* __restrict__ hP,
                                               const float* __restrict__ fcb,
                                               float* __restrict__ logits){
  __shared__ float ld[32][65];
  int lane = threadIdx.x & 63, w = threadIdx.x >> 6;
  int v0 = blockIdx.x * 64 + w * 16;
  f32x4 acc0 = {0,0,0,0}, acc1 = {0,0,0,0};
  mfma_tile<ABF16>(fcW, Hdim, v0, hP, 0, Hdim, lane, acc0, acc1);
  int q = lane >> 4, c = lane & 15;
#pragma unroll
  for (int rr = 0; rr < 4; rr++){
    int vloc = w * 16 + q * 4 + rr;
    ld[c][vloc]      = acc0[rr];
    ld[c + 16][vloc] = acc1[rr];
  }
  __syncthreads();
  int b = threadIdx.x >> 3, i8 = (threadIdx.x & 7) * 8;
  int vg = blockIdx.x * 64 + i8;
  float4 o0, o1;
  o0.x = ld[b][i8+0] + fcb[vg+0]; o0.y = ld[b][i8+1] + fcb[vg+1];
  o0.z = ld[b][i8+2] + fcb[vg+2]; o0.w = ld[b][i8+3] + fcb[vg+3];
  o1.x = ld[b][i8+4] + fcb[vg+4]; o1.y = ld[b][i8+5] + fcb[vg+5];
  o1.z = ld[b][i8+6] + fcb[vg+6]; o1.w = ld[b][i8+7] + fcb[vg+7];
  *(float4*)&logits[(size_t)b * Vdim + vg]     = o0;
  *(float4*)&logits[(size_t)b * Vdim + vg + 4] = o1;
}

// ============ log-softmax over V: reduce then write ============
__global__ __launch_bounds__(1024) void lsm_reduce(const float* __restrict__ logits,
                                                   float* __restrict__ lse){
  __shared__ float red[1024];
  int b = blockIdx.x, tid = threadIdx.x;
  const float4* row4 = (const float4*)(logits + (size_t)b * Vdim);
  float m = -1e30f;
  for (int i = tid; i < Vdim / 4; i += 1024){
    float4 v = row4[i];
    m = fmaxf(m, fmaxf(fmaxf(v.x, v.y), fmaxf(v.z, v.w)));
  }
  red[tid] = m; __syncthreads();
  for (int s = 512; s; s >>= 1){
    if (tid < s) red[tid] = fmaxf(red[tid], red[tid + s]);
    __syncthreads();
  }
  m = red[0]; __syncthreads();
  float sum = 0.0f;
  for (int i = tid; i < Vdim / 4; i += 1024){
    float4 v = row4[i];
    sum += expf(v.x - m) + expf(v.y - m) + expf(v.z - m) + expf(v.w - m);
  }
  red[tid] = sum; __syncthreads();
  for (int s = 512; s; s >>= 1){
    if (tid < s) red[tid] += red[tid + s];
    __syncthreads();
  }
  if (tid == 0) lse[b] = m + logf(red[0]);
}

__global__ __launch_bounds__(256) void lsm_write(const float* __restrict__ logits,
                                                 const float* __restrict__ lse,
                                                 float* __restrict__ out, int t){
  int i = blockIdx.x * 256 + threadIdx.x;   // float4 idx, 256000 total
  if (i >= Bdim * Vdim / 4) return;
  int b = i / (Vdim / 4);
  float l = lse[b];
  float4 v = ((const float4*)logits)[i];
  float4* dst = (float4*)(out + ((size_t)b * Tdim + t) * Vdim);
  dst[i - b * (Vdim / 4)] = make_float4(v.x - l, v.y - l, v.z - l, v.w - l);
}

// =====================================================================
extern "C" void kernel_launch(void* const* d_in, const int* in_sizes, int n_in,
                              void* d_out, int out_size, void* d_ws, size_t ws_size,
                              hipStream_t stream){
  const float* x    = (const float*)d_in[0];
  const int*   tseq = (const int*)  d_in[1];
  const float* emb  = (const float*)d_in[2];
  const float* aW1  = (const float*)d_in[3];
  const float* ab1  = (const float*)d_in[4];
  const float* aW2  = (const float*)d_in[5];
  const float* ab2  = (const float*)d_in[6];
  const float* fcW  = (const float*)d_in[7];
  const float* fcb  = (const float*)d_in[8];
  const float* Wih[3] = {(const float*)d_in[9],  (const float*)d_in[13], (const float*)d_in[17]};
  const float* Whh[3] = {(const float*)d_in[10], (const float*)d_in[14], (const float*)d_in[18]};
  const float* bih[3] = {(const float*)d_in[11], (const float*)d_in[15], (const float*)d_in[19]};
  const float* bhh[3] = {(const float*)d_in[12], (const float*)d_in[16], (const float*)d_in[20]};
  float* out = (float*)d_out;

  // ---- workspace carve-up (bytes) ----
  char* p = (char*)d_ws;
  ushort* xW_bf  = (ushort*)p;            p += (size_t)4096 * 1024 * 2;       // 8.39 MB
  ushort* W1h_bf = (ushort*)p;            p += (size_t)1024 * 1024 * 2;       // 2.10 MB
  ushort* inpP   = (ushort*)p;            p += (size_t)Tdim * 49152 * 2;      // 4.92 MB
  float*  aPart  = (float*)p;             p += (size_t)4 * 32768 * 4;         // 0.52 MB
  float*  scBuf  = (float*)p;             p += (size_t)Bdim * Sdim * 4;       // 16 KB
  float*  lseBuf = (float*)p;             p += 256;
  float*  gPart  = (float*)p;             p += (size_t)4 * 131072 * 4;        // 2.10 MB
  float*  logits = (float*)p;             p += (size_t)Bdim * Vdim * 4;       // 4.10 MB
  float*  cBuf   = (float*)p;             p += (size_t)6 * 32768 * 4;         // 0.79 MB
  ushort* hPackB = (ushort*)p;            p += (size_t)6 * 32768 * 2;         // 0.39 MB
  // full-precision-weight conversions (only if workspace allows)
  ushort* fcW_bf  = (ushort*)p;           p += (size_t)Vdim * Hdim * 2;       // 65.5 MB
  ushort* Wih_bf[3]; ushort* Whh_bf[3];
  Wih_bf[0] = (ushort*)p;                 p += (size_t)4096 * 1536 * 2;
  Whh_bf[0] = (ushort*)p;                 p += (size_t)4096 * 1024 * 2;
  Wih_bf[1] = (ushort*)p;                 p += (size_t)4096 * 1024 * 2;
  Whh_bf[1] = (ushort*)p;                 p += (size_t)4096 * 1024 * 2;
  Wih_bf[2] = (ushort*)p;                 p += (size_t)4096 * 1024 * 2;
  Whh_bf[2] = (ushort*)p;                 p += (size_t)4096 * 1024 * 2;
  size_t need_full = (size_t)(p - (char*)d_ws);
  bool full = ws_size >= need_full;

  // ---- setup ----
  // zero c (6*32768 f32) + hPack (6*32768 ushort = 3*32768 f32-words), contiguous
  zero_kernel<<<(294912 + 255) / 256, 256, 0, stream>>>(cBuf, 294912);
  gather_emb_p<<<(Tdim * Bdim * 96 + 255) / 256, 256, 0, stream>>>(tseq, emb, inpP);
  cvt_w1h<<<262144 / 256, 256, 0, stream>>>(aW1, W1h_bf);
  xw_gemm<<<dim3(64, 16), 256, 0, stream>>>(x, aW1, xW_bf);
  if (full){
    cvt_bf16<<<(Vdim * Hdim / 4 + 255) / 256, 256, 0, stream>>>(fcW, fcW_bf, Vdim * Hdim / 4);
    cvt_bf16<<<(4096 * 1536 / 4 + 255) / 256, 256, 0, stream>>>(Wih[0], Wih_bf[0], 4096 * 1536 / 4);
    cvt_bf16<<<(4096 * 1024 / 4 + 255) / 256, 256, 0, stream>>>(Whh[0], Whh_bf[0], 4096 * 1024 / 4);
    cvt_bf16<<<(4096 * 1024 / 4 + 255) / 256, 256, 0, stream>>>(Wih[1], Wih_bf[1], 4096 * 1024 / 4);
    cvt_bf16<<<(4096 * 1024 / 4 + 255) / 256, 256, 0, stream>>>(Whh[1], Whh_bf[1], 4096 * 1024 / 4);
    cvt_bf16<<<(4096 * 1024 / 4 + 255) / 256, 256, 0, stream>>>(Wih[2], Wih_bf[2], 4096 * 1024 / 4);
    cvt_bf16<<<(4096 * 1024 / 4 + 255) / 256, 256, 0, stream>>>(Whh[2], Whh_bf[2], 4096 * 1024 / 4);
  }

  #define HP(l, par)  (hPackB + ((l) * 2 + (par)) * 32768)
  #define CB(l, par)  (cBuf   + ((l) * 2 + (par)) * 32768)

  for (int t = 0; t < Tdim; t++){
    int pn = t & 1, po = 1 - pn;
    ushort* inpPt = inpP + (size_t)t * 49152;

    attn_a_gemm<<<dim3(16, 4), 256, 0, stream>>>(W1h_bf, HP(2, po), aPart);
    attn_score<<<128, 256, 0, stream>>>(aPart, ab1, aW2, ab2, xW_bf, scBuf);
    attn_ctx2<<<96, 256, 0, stream>>>(scBuf, x, inpPt);

    for (int l = 0; l < 3; l++){
      const ushort* bin = (l == 0) ? inpPt : HP(l - 1, pn);
      int kin = (l == 0) ? INPD : Hdim;
      if (full)
        gate_gemm<true ><<<dim3(64, 4), 256, 0, stream>>>(Wih_bf[l], kin, Whh_bf[l], bin, HP(l, po), gPart);
      else
        gate_gemm<false><<<dim3(64, 4), 256, 0, stream>>>(Wih[l],    kin, Whh[l],    bin, HP(l, po), gPart);
      cell_update<<<128, 256, 0, stream>>>(gPart, bih[l], bhh[l], CB(l, po), CB(l, pn), HP(l, pn));
    }

    if (full) fc_gemm<true ><<<Vdim / 64, 256, 0, stream>>>(fcW_bf, HP(2, pn), fcb, logits);
    else      fc_gemm<false><<<Vdim / 64, 256, 0, stream>>>(fcW,    HP(2, pn), fcb, logits);
    lsm_reduce<<<Bdim, 1024, 0, stream>>>(logits, lseBuf);
    lsm_write<<<(Bdim * Vdim / 4 + 255) / 256, 256, 0, stream>>>(logits, lseBuf, out, t);
  }
}